// Round 1
// baseline (2939.273 us; speedup 1.0000x reference)
//
#include <hip/hip_runtime.h>
#include <math.h>

// Problem constants
constexpr int Bc  = 64;
constexpr int Sc  = 1024;
constexpr int Dc  = 768;
constexpr int ISc = 307;   // int(S*0.3)
constexpr int IDc = 230;   // int(D*0.3)
constexpr long GSTRIDE = 235776; // per-batch stride of gelu intermediate (= IS*D >= S*ID)

// ---------------- conditional LayerNorm ----------------
// one 256-thread block per row (D=768 => 3 elems/thread)
__global__ __launch_bounds__(256) void cond_ln_kernel(
    const float* __restrict__ x, const int* __restrict__ tasks,
    const float* __restrict__ cln, float* __restrict__ out)
{
    const int row = blockIdx.x;          // b*S + n
    const int b   = row >> 10;           // / S (S=1024)
    const int t   = tasks[b];
    const float* xr   = x + (size_t)row * Dc;
    float*       outr = out + (size_t)row * Dc;
    const float* gamma = cln + (size_t)t * (2 * Dc);
    const float* beta  = gamma + Dc;

    const int tid = threadIdx.x;
    const float v0 = xr[tid];
    const float v1 = xr[tid + 256];
    const float v2 = xr[tid + 512];
    float s = v0 + v1 + v2;
    float q = v0 * v0 + v1 * v1 + v2 * v2;
    #pragma unroll
    for (int o = 1; o < 64; o <<= 1) {
        s += __shfl_xor(s, o, 64);
        q += __shfl_xor(q, o, 64);
    }
    __shared__ float sm_s[4], sm_q[4];
    const int w = tid >> 6;
    if ((tid & 63) == 0) { sm_s[w] = s; sm_q[w] = q; }
    __syncthreads();
    s = sm_s[0] + sm_s[1] + sm_s[2] + sm_s[3];
    q = sm_q[0] + sm_q[1] + sm_q[2] + sm_q[3];
    const float mu  = s * (1.0f / Dc);
    float var = q * (1.0f / Dc) - mu * mu;
    var = var < 0.0f ? 0.0f : var;
    const float rstd = 1.0f / sqrtf(var + 1e-5f);
    outr[tid]       = gamma[tid]       * ((v0 - mu) * rstd) + beta[tid];
    outr[tid + 256] = gamma[tid + 256] * ((v1 - mu) * rstd) + beta[tid + 256];
    outr[tid + 512] = gamma[tid + 512] * ((v2 - mu) * rstd) + beta[tid + 512];
}

// ---------------- batched fp32 GEMM ----------------
// C[b] (MxN) = A[sel] (MxK, row-major) * B[sel] (KxN row-major, or NxK row-major if BT)
// optional exact GELU on result, optional residual add (R[b], MxN row-major).
template<bool BT, bool DO_GELU, bool RES_IN, bool A_TASK, bool B_TASK>
__global__ __launch_bounds__(256) void gemm_kernel(
    const float* __restrict__ A, const float* __restrict__ Bm,
    const float* __restrict__ R, float* __restrict__ C,
    const int* __restrict__ tasks,
    int M, int N, int K,
    long sA, long sB, long sR, long sC)
{
    constexpr int BM = 64, BN = 64, BK = 16;
    const int b = blockIdx.z;
    const int t = tasks[b];
    const float* Ab = A  + (A_TASK ? (long)t : (long)b) * sA;
    const float* Bb = Bm + (B_TASK ? (long)t : (long)b) * sB;
    const float* Rb = RES_IN ? (R + (long)b * sR) : nullptr;
    float*       Cb = C  + (long)b * sC;

    __shared__ float As[BK][BM + 1];
    __shared__ float Bs[BK][BN + 1];

    const int tid   = threadIdx.x;
    const int mBase = blockIdx.y * BM;
    const int nBase = blockIdx.x * BN;
    const int tr = tid >> 4;   // 0..15 (row group)
    const int tc = tid & 15;   // 0..15 (col group)

    float acc[4][4] = {};

    for (int k0 = 0; k0 < K; k0 += BK) {
        // A tile: As[k][m] = A[mBase+m][k0+k]
        #pragma unroll
        for (int i = 0; i < 4; i++) {
            const int idx = tid + i * 256;
            const int m = idx >> 4, k = idx & 15;
            const int gm = mBase + m, gk = k0 + k;
            As[k][m] = (gm < M && gk < K) ? Ab[(long)gm * K + gk] : 0.0f;
        }
        // B tile: Bs[k][n]
        if (!BT) {
            #pragma unroll
            for (int i = 0; i < 4; i++) {
                const int idx = tid + i * 256;
                const int k = idx >> 6, n = idx & 63;
                const int gk = k0 + k, gn = nBase + n;
                Bs[k][n] = (gk < K && gn < N) ? Bb[(long)gk * N + gn] : 0.0f;
            }
        } else {
            #pragma unroll
            for (int i = 0; i < 4; i++) {
                const int idx = tid + i * 256;
                const int n = idx >> 4, k = idx & 15;
                const int gk = k0 + k, gn = nBase + n;
                Bs[k][n] = (gk < K && gn < N) ? Bb[(long)gn * K + gk] : 0.0f;
            }
        }
        __syncthreads();
        #pragma unroll
        for (int kk = 0; kk < BK; kk++) {
            float a[4], bb[4];
            #pragma unroll
            for (int i = 0; i < 4; i++) a[i] = As[kk][tr * 4 + i];
            #pragma unroll
            for (int j = 0; j < 4; j++) bb[j] = Bs[kk][tc * 4 + j];
            #pragma unroll
            for (int i = 0; i < 4; i++)
                #pragma unroll
                for (int j = 0; j < 4; j++)
                    acc[i][j] = fmaf(a[i], bb[j], acc[i][j]);
        }
        __syncthreads();
    }

    #pragma unroll
    for (int i = 0; i < 4; i++) {
        const int gm = mBase + tr * 4 + i;
        if (gm >= M) continue;
        #pragma unroll
        for (int j = 0; j < 4; j++) {
            const int gn = nBase + tc * 4 + j;
            if (gn >= N) continue;
            float v = acc[i][j];
            if (DO_GELU) v = 0.5f * v * (1.0f + erff(v * 0.70710678118654752f));
            if (RES_IN)  v += Rb[(long)gm * N + gn];
            Cb[(long)gm * N + gn] = v;
        }
    }
}

extern "C" void kernel_launch(void* const* d_in, const int* in_sizes, int n_in,
                              void* d_out, int out_size, void* d_ws, size_t ws_size,
                              hipStream_t stream) {
    const float* x      = (const float*)d_in[0];
    const int*   tasks  = (const int*)  d_in[1];
    const float* cln1   = (const float*)d_in[2];
    const float* cln2   = (const float*)d_in[3];
    const float* w1_tok = (const float*)d_in[4];
    const float* w2_tok = (const float*)d_in[5];
    const float* w1_ch  = (const float*)d_in[6];
    const float* w2_ch  = (const float*)d_in[7];
    float* out = (float*)d_out;

    float* h = (float*)d_ws;                      // B*S*D   (x1 = x + token-mix)
    float* g = h + (size_t)Bc * Sc * Dc;          // B*GSTRIDE (gelu intermediates)

    const dim3 blk(256);

    // 1) h1 = condLN(x, cln1) -> stored in d_out (temp)
    cond_ln_kernel<<<Bc * Sc, blk, 0, stream>>>(x, tasks, cln1, out);

    // 2) g = gelu( w1_tok[t] (ISxS) @ h1 (SxD) )          [NN]
    gemm_kernel<false, true, false, true, false>
        <<<dim3(Dc / 64, (ISc + 63) / 64, Bc), blk, 0, stream>>>(
        w1_tok, out, nullptr, g, tasks,
        ISc, Dc, Sc, (long)ISc * Sc, (long)Sc * Dc, 0, GSTRIDE);

    // 3) x1 = x + w2_tok[t] (SxIS) @ g (ISxD) -> ws.h     [NN + residual]
    gemm_kernel<false, false, true, true, false>
        <<<dim3(Dc / 64, Sc / 64, Bc), blk, 0, stream>>>(
        w2_tok, g, x, h, tasks,
        Sc, Dc, ISc, (long)Sc * ISc, GSTRIDE, (long)Sc * Dc, (long)Sc * Dc);

    // 4) h2 = condLN(x1, cln2) -> d_out (temp)
    cond_ln_kernel<<<Bc * Sc, blk, 0, stream>>>(h, tasks, cln2, out);

    // 5) g = gelu( h2 (SxD) @ w1_ch[t]^T (DxID) )         [NT]
    gemm_kernel<true, true, false, false, true>
        <<<dim3((IDc + 63) / 64, Sc / 64, Bc), blk, 0, stream>>>(
        out, w1_ch, nullptr, g, tasks,
        Sc, IDc, Dc, (long)Sc * Dc, (long)IDc * Dc, 0, GSTRIDE);

    // 6) out = x1 + g (SxID) @ w2_ch[t]^T (IDxD)          [NT + residual]
    gemm_kernel<true, false, true, false, true>
        <<<dim3(Dc / 64, Sc / 64, Bc), blk, 0, stream>>>(
        g, w2_ch, h, out, tasks,
        Sc, Dc, IDc, GSTRIDE, (long)Dc * IDc, (long)Sc * Dc, (long)Sc * Dc);
}

// Round 2
// 766.681 us; speedup vs baseline: 3.8338x; 3.8338x over previous
//
#include <hip/hip_runtime.h>
#include <math.h>

typedef __bf16 bf16x8 __attribute__((ext_vector_type(8)));
typedef __bf16 bf16x4 __attribute__((ext_vector_type(4)));
typedef float  f32x4  __attribute__((ext_vector_type(4)));

constexpr int Bc = 64, Sc = 1024, Dc = 768, ISc = 307, IDc = 230;
constexpr int ISp = 312;  // IS padded to x8 (zero-filled)
constexpr int IDp = 232;  // ID padded to x8 (zero-filled)

// ---------------- fp32 -> bf16 convert with row padding (pad = zeros) ------
__global__ __launch_bounds__(256) void cvt_pad(
    const float* __restrict__ in, __bf16* __restrict__ out,
    int rows, int incols, int outcols)
{
    const int cpr = outcols >> 3;               // 8-elem chunks per row
    const int c   = blockIdx.x * 256 + threadIdx.x;
    if (c >= rows * cpr) return;
    const int r  = c / cpr;
    const int cc = (c - r * cpr) * 8;
    const float* src = in + (long)r * incols + cc;
    bf16x8 o;
    #pragma unroll
    for (int e = 0; e < 8; e++)
        o[e] = (cc + e < incols) ? (__bf16)src[e] : (__bf16)0.0f;
    *reinterpret_cast<bf16x8*>(out + (long)r * outcols + cc) = o;
}

// ---------------- conditional LayerNorm (fp32 in, bf16 out) ----------------
// 192 threads/block, one block per row, float4 loads
__global__ __launch_bounds__(192) void cond_ln(
    const float* __restrict__ x, const int* __restrict__ tasks,
    const float* __restrict__ cln, __bf16* __restrict__ out)
{
    const int row = blockIdx.x;
    const int b   = row >> 10;                  // /S
    const int t   = tasks[b];
    const int tid = threadIdx.x;
    const float4 v = reinterpret_cast<const float4*>(x + (long)row * Dc)[tid];
    float s = v.x + v.y + v.z + v.w;
    float q = v.x * v.x + v.y * v.y + v.z * v.z + v.w * v.w;
    #pragma unroll
    for (int o = 1; o < 64; o <<= 1) { s += __shfl_xor(s, o); q += __shfl_xor(q, o); }
    __shared__ float ss[3], qs[3];
    const int w = tid >> 6;
    if ((tid & 63) == 0) { ss[w] = s; qs[w] = q; }
    __syncthreads();
    s = ss[0] + ss[1] + ss[2];
    q = qs[0] + qs[1] + qs[2];
    const float mu   = s * (1.0f / Dc);
    const float var  = fmaxf(q * (1.0f / Dc) - mu * mu, 0.0f);
    const float rstd = 1.0f / sqrtf(var + 1e-5f);
    const float4 g  = reinterpret_cast<const float4*>(cln + (long)t * 2 * Dc)[tid];
    const float4 be = reinterpret_cast<const float4*>(cln + (long)t * 2 * Dc + Dc)[tid];
    bf16x4 o;
    o[0] = (__bf16)(g.x * ((v.x - mu) * rstd) + be.x);
    o[1] = (__bf16)(g.y * ((v.y - mu) * rstd) + be.y);
    o[2] = (__bf16)(g.z * ((v.z - mu) * rstd) + be.z);
    o[3] = (__bf16)(g.w * ((v.w - mu) * rstd) + be.w);
    *reinterpret_cast<bf16x4*>(out + (long)row * Dc + tid * 4) = o;
}

// ---------------- bf16 tiled transpose: in (rows x cols) -> outT (cols x rows)
// grid: (rows/64, cols/64, B). XOR-swizzled LDS to avoid bank conflicts.
__global__ __launch_bounds__(256) void transpose_bf16(
    const __bf16* __restrict__ in, __bf16* __restrict__ outT, int rows, int cols)
{
    __shared__ unsigned short T[64][72];
    const long ib = (long)blockIdx.z * rows * cols;
    const int r0 = blockIdx.x * 64, c0 = blockIdx.y * 64;
    const int tid = threadIdx.x;
    #pragma unroll
    for (int rep = 0; rep < 2; rep++) {
        const int c = rep * 256 + tid;
        const int rl = c >> 3, cc = (c & 7) * 8;
        const uint4 v = *reinterpret_cast<const uint4*>(in + ib + (long)(r0 + rl) * cols + c0 + cc);
        const int chunk = (cc >> 3) ^ ((rl >> 3) & 7);
        *reinterpret_cast<uint4*>(&T[rl][chunk * 8]) = v;
    }
    __syncthreads();
    #pragma unroll
    for (int rep = 0; rep < 2; rep++) {
        const int c = rep * 256 + tid;
        const int cl = c >> 3, rc = (c & 7) * 8;
        unsigned short tmp[8];
        #pragma unroll
        for (int e = 0; e < 8; e++) {
            const int rr = rc + e;
            const int chunk = (cl >> 3) ^ ((rr >> 3) & 7);
            tmp[e] = T[rr][(chunk << 3) | (cl & 7)];
        }
        *reinterpret_cast<uint4*>(outT + ib + (long)(c0 + cl) * rows + r0 + rc) =
            *reinterpret_cast<uint4*>(tmp);
    }
}

// ---------------- x1 = x + C3T^T : cT is (D x S) bf16 per batch ------------
// grid: (S/64, D/64, B)
__global__ __launch_bounds__(256) void add_transpose(
    const __bf16* __restrict__ cT, const float* __restrict__ x, float* __restrict__ x1)
{
    __shared__ unsigned short T[64][72];
    const int s0 = blockIdx.x * 64, d0 = blockIdx.y * 64;
    const long ib = (long)blockIdx.z * Sc * Dc;
    const int tid = threadIdx.x;
    #pragma unroll
    for (int rep = 0; rep < 2; rep++) {
        const int c = rep * 256 + tid;
        const int dl = c >> 3, sc = (c & 7) * 8;
        const uint4 v = *reinterpret_cast<const uint4*>(cT + ib + (long)(d0 + dl) * Sc + s0 + sc);
        const int chunk = (sc >> 3) ^ ((dl >> 3) & 7);
        *reinterpret_cast<uint4*>(&T[dl][chunk * 8]) = v;
    }
    __syncthreads();
    #pragma unroll
    for (int rep = 0; rep < 2; rep++) {
        const int c = rep * 256 + tid;
        const int sl = c >> 3, dc = (c & 7) * 8;
        const float* xs = x + ib + (long)(s0 + sl) * Dc + d0 + dc;
        float* os = x1 + ib + (long)(s0 + sl) * Dc + d0 + dc;
        float4 a = reinterpret_cast<const float4*>(xs)[0];
        float4 b2 = reinterpret_cast<const float4*>(xs)[1];
        float o[8];
        #pragma unroll
        for (int e = 0; e < 8; e++) {
            const int dd = dc + e;
            const int chunk = (sl >> 3) ^ ((dd >> 3) & 7);
            const unsigned int u = ((unsigned int)T[dd][(chunk << 3) | (sl & 7)]) << 16;
            o[e] = __builtin_bit_cast(float, u);
        }
        float4 r1 = {a.x + o[0], a.y + o[1], a.z + o[2], a.w + o[3]};
        float4 r2 = {b2.x + o[4], b2.y + o[5], b2.z + o[6], b2.w + o[7]};
        reinterpret_cast<float4*>(os)[0] = r1;
        reinterpret_cast<float4*>(os)[1] = r2;
    }
}

// ---------------- bf16 TN MFMA GEMM ----------------------------------------
// C[b] (MxN) = A[b] (MxK, k-contig, lda) * B[task]^T (B stored NxK, k-contig, ldb)
// M always multiple of 128. N may tail (guard). K multiple of 8 (pads zeroed).
template<bool DO_GELU, bool RES_IN, bool OUT_F32>
__global__ __launch_bounds__(256, 2) void gemm_tn(
    const __bf16* __restrict__ A, long sA, int lda,
    const __bf16* __restrict__ B, long sB, int ldb,
    const float* __restrict__ R, long sR,
    void* __restrict__ C, long sC, int ldc,
    const int* __restrict__ tasks,
    int M, int N, int K, int Nout)
{
    constexpr int BM = 128, BN = 128, BK = 64, LDP = BK + 8;
    __shared__ unsigned short As[BM][LDP];
    __shared__ unsigned short Bs[BN][LDP];

    const int b = blockIdx.z;
    const int t = tasks[b];
    const __bf16* Ab = A + (long)b * sA;
    const __bf16* Bb = B + (long)t * sB;
    const int m0 = blockIdx.y * BM, n0 = blockIdx.x * BN;
    const int tid = threadIdx.x, lane = tid & 63, wid = tid >> 6;
    const int wm = (wid >> 1) * 64, wn = (wid & 1) * 64;
    const int l15 = lane & 15, l4 = lane >> 4;

    f32x4 acc[4][4];
    #pragma unroll
    for (int i = 0; i < 4; i++)
        #pragma unroll
        for (int j = 0; j < 4; j++)
            acc[i][j] = (f32x4){0.f, 0.f, 0.f, 0.f};

    for (int k0 = 0; k0 < K; k0 += BK) {
        // stage A: BM x BK
        #pragma unroll
        for (int rep = 0; rep < 4; rep++) {
            const int c = rep * 256 + tid;
            const int m = c >> 3, kc = (c & 7) * 8;
            const int gk = k0 + kc;
            uint4 v = {0u, 0u, 0u, 0u};
            if (gk + 8 <= K) {
                v = *reinterpret_cast<const uint4*>(Ab + (long)(m0 + m) * lda + gk);
            } else if (gk < K) {
                unsigned short tmp[8];
                const unsigned short* s = (const unsigned short*)(Ab + (long)(m0 + m) * lda + gk);
                #pragma unroll
                for (int e = 0; e < 8; e++) tmp[e] = (gk + e < K) ? s[e] : 0;
                v = *reinterpret_cast<uint4*>(tmp);
            }
            *reinterpret_cast<uint4*>(&As[m][kc]) = v;
        }
        // stage B: BN x BK (rows are output-cols n)
        #pragma unroll
        for (int rep = 0; rep < 4; rep++) {
            const int c = rep * 256 + tid;
            const int n = c >> 3, kc = (c & 7) * 8;
            const int gk = k0 + kc, gn = n0 + n;
            uint4 v = {0u, 0u, 0u, 0u};
            if (gn < N) {
                if (gk + 8 <= K) {
                    v = *reinterpret_cast<const uint4*>(Bb + (long)gn * ldb + gk);
                } else if (gk < K) {
                    unsigned short tmp[8];
                    const unsigned short* s = (const unsigned short*)(Bb + (long)gn * ldb + gk);
                    #pragma unroll
                    for (int e = 0; e < 8; e++) tmp[e] = (gk + e < K) ? s[e] : 0;
                    v = *reinterpret_cast<uint4*>(tmp);
                }
            }
            *reinterpret_cast<uint4*>(&Bs[n][kc]) = v;
        }
        __syncthreads();
        #pragma unroll
        for (int h = 0; h < 2; h++) {
            bf16x8 af[4], bf[4];
            #pragma unroll
            for (int i = 0; i < 4; i++)
                af[i] = *reinterpret_cast<const bf16x8*>(&As[wm + i * 16 + l15][h * 32 + l4 * 8]);
            #pragma unroll
            for (int j = 0; j < 4; j++)
                bf[j] = *reinterpret_cast<const bf16x8*>(&Bs[wn + j * 16 + l15][h * 32 + l4 * 8]);
            #pragma unroll
            for (int i = 0; i < 4; i++)
                #pragma unroll
                for (int j = 0; j < 4; j++)
                    acc[i][j] = __builtin_amdgcn_mfma_f32_16x16x32_bf16(af[i], bf[j], acc[i][j], 0, 0, 0);
        }
        __syncthreads();
    }

    float* Cf = (float*)C + (long)b * sC;
    __bf16* Ch = (__bf16*)C + (long)b * sC;
    const float* Rb = RES_IN ? (R + (long)b * sR) : nullptr;

    #pragma unroll
    for (int i = 0; i < 4; i++) {
        #pragma unroll
        for (int j = 0; j < 4; j++) {
            const int gn = n0 + wn + j * 16 + l15;
            if (gn >= Nout) continue;
            #pragma unroll
            for (int r = 0; r < 4; r++) {
                const int gm = m0 + wm + i * 16 + l4 * 4 + r;
                float v = acc[i][j][r];
                if (DO_GELU) v = 0.5f * v * (1.0f + erff(v * 0.70710678118654752f));
                if (RES_IN)  v += Rb[(long)gm * ldc + gn];
                if (OUT_F32) Cf[(long)gm * ldc + gn] = v;
                else         Ch[(long)gm * ldc + gn] = (__bf16)v;
            }
        }
    }
}

extern "C" void kernel_launch(void* const* d_in, const int* in_sizes, int n_in,
                              void* d_out, int out_size, void* d_ws, size_t ws_size,
                              hipStream_t stream) {
    const float* x      = (const float*)d_in[0];
    const int*   tasks  = (const int*)  d_in[1];
    const float* cln1   = (const float*)d_in[2];
    const float* cln2   = (const float*)d_in[3];
    const float* w1_tok = (const float*)d_in[4];
    const float* w2_tok = (const float*)d_in[5];
    const float* w1_ch  = (const float*)d_in[6];
    const float* w2_ch  = (const float*)d_in[7];
    float* out = (float*)d_out;

    // workspace layout (all 16B aligned)
    char* ws = (char*)d_ws;
    const long szT1 = (long)10 * ISc * Sc * 2;   // 6287360
    const long szT2 = (long)10 * Sc * ISp * 2;   // 6389760
    const long szC1 = (long)10 * IDc * Dc * 2;   // 3532800
    const long szC2 = (long)10 * Dc * IDp * 2;   // 3563520
    __bf16* wT1 = (__bf16*)ws;
    __bf16* wT2 = (__bf16*)(ws + szT1);
    __bf16* wC1 = (__bf16*)(ws + szT1 + szT2);
    __bf16* wC2 = (__bf16*)(ws + szT1 + szT2 + szC1);
    __bf16* actT = (__bf16*)(ws + szT1 + szT2 + szC1 + szC2);      // 64*768*1024 bf16
    __bf16* gbuf = (__bf16*)(ws + szT1 + szT2 + szC1 + szC2 + (long)Bc * Dc * Sc * 2);

    const dim3 blk(256);

    // weight conversion (padded, zero-filled)
    cvt_pad<<<(10 * ISc * (Sc / 8) + 255) / 256, blk, 0, stream>>>(w1_tok, wT1, 10 * ISc, Sc, Sc);
    cvt_pad<<<(10 * Sc  * (ISp / 8) + 255) / 256, blk, 0, stream>>>(w2_tok, wT2, 10 * Sc, ISc, ISp);
    cvt_pad<<<(10 * IDc * (Dc / 8) + 255) / 256, blk, 0, stream>>>(w1_ch, wC1, 10 * IDc, Dc, Dc);
    cvt_pad<<<(10 * Dc  * (IDp / 8) + 255) / 256, blk, 0, stream>>>(w2_ch, wC2, 10 * Dc, IDc, IDp);

    // 1) h1 = condLN(x, cln1) -> bf16 in d_out scratch
    cond_ln<<<Bc * Sc, 192, 0, stream>>>(x, tasks, cln1, (__bf16*)d_out);
    // 2) h1T (D x S per batch)
    transpose_bf16<<<dim3(Sc / 64, Dc / 64, Bc), blk, 0, stream>>>((const __bf16*)d_out, actT, Sc, Dc);
    // 3) GT = gelu(h1T @ W1tok^T)   (768 x ISp per batch)
    gemm_tn<true, false, false><<<dim3((ISp + 127) / 128, Dc / 128, Bc), blk, 0, stream>>>(
        actT, (long)Dc * Sc, Sc,
        wT1, (long)ISc * Sc, Sc,
        nullptr, 0,
        gbuf, (long)Dc * ISp, ISp,
        tasks, Dc, ISc, Sc, ISp);
    // 4) C3T = GT @ W2tok^T          (768 x 1024 per batch)
    gemm_tn<false, false, false><<<dim3(Sc / 128, Dc / 128, Bc), blk, 0, stream>>>(
        gbuf, (long)Dc * ISp, ISp,
        wT2, (long)Sc * ISp, ISp,
        nullptr, 0,
        actT, (long)Dc * Sc, Sc,
        tasks, Dc, Sc, ISp, Sc);
    // 5) x1 = x + C3T^T -> fp32 in d_out
    add_transpose<<<dim3(Sc / 64, Dc / 64, Bc), blk, 0, stream>>>(actT, x, out);
    // 6) h2 = condLN(x1, cln2) -> bf16 (reuse actT)
    cond_ln<<<Bc * Sc, 192, 0, stream>>>(out, tasks, cln2, actT);
    // 7) G2 = gelu(h2 @ W1ch^T)      (1024 x IDp per batch, reuse gbuf)
    gemm_tn<true, false, false><<<dim3((IDp + 127) / 128, Sc / 128, Bc), blk, 0, stream>>>(
        actT, (long)Sc * Dc, Dc,
        wC1, (long)IDc * Dc, Dc,
        nullptr, 0,
        gbuf, (long)Sc * IDp, IDp,
        tasks, Sc, IDc, Dc, IDp);
    // 8) out = x1 + G2 @ W2ch^T      (in-place residual, fp32)
    gemm_tn<false, true, true><<<dim3(Dc / 128, Sc / 128, Bc), blk, 0, stream>>>(
        gbuf, (long)Sc * IDp, IDp,
        wC2, (long)Dc * IDp, IDp,
        out, (long)Sc * Dc,
        out, (long)Sc * Dc, Dc,
        tasks, Sc, Dc, IDp, Dc);
}

// Round 4
// 752.377 us; speedup vs baseline: 3.9067x; 1.0190x over previous
//
#include <hip/hip_runtime.h>
#include <math.h>

typedef __bf16 bf16x8 __attribute__((ext_vector_type(8)));
typedef __bf16 bf16x4 __attribute__((ext_vector_type(4)));
typedef float  f32x4  __attribute__((ext_vector_type(4)));

constexpr int Bc = 64, Sc = 1024, Dc = 768;
constexpr int ISc = 307, IDc = 230;
constexpr int ISp = 312, IDp = 232;   // padded to x8, zero-filled

static __device__ __forceinline__ float bf2f(unsigned short u) {
    return __builtin_bit_cast(float, (unsigned)u << 16);
}

// ---------------- fp32 -> bf16 convert, task-major, row+col zero padding ---
__global__ __launch_bounds__(256) void cvt_pad(
    const float* __restrict__ in, __bf16* __restrict__ out,
    int inrows, int outrows, int incols, int outcols)
{
    const int cpr = outcols >> 3;
    const long c = (long)blockIdx.x * 256 + threadIdx.x;
    if (c >= (long)10 * outrows * cpr) return;
    const int perT = outrows * cpr;
    const int t    = (int)(c / perT);
    const int rem  = (int)(c - (long)t * perT);
    const int r    = rem / cpr;
    const int cc   = (rem - r * cpr) * 8;
    bf16x8 o;
    if (r < inrows) {
        const float* src = in + ((long)t * inrows + r) * incols + cc;
        #pragma unroll
        for (int e = 0; e < 8; e++)
            o[e] = (cc + e < incols) ? (__bf16)src[e] : (__bf16)0.0f;
    } else {
        #pragma unroll
        for (int e = 0; e < 8; e++) o[e] = (__bf16)0.0f;
    }
    *reinterpret_cast<bf16x8*>(out + ((long)t * outrows + r) * outcols + cc) = o;
}

// ---------------- LN1 fused with transpose: x (B,S,D) fp32 -> h1T (B,D,S) bf16
// 256 threads, 32 s-rows per block; 8 threads per row (96 floats each).
__global__ __launch_bounds__(256) void ln1_t(
    const float* __restrict__ x, const int* __restrict__ tasks,
    const float* __restrict__ cln, __bf16* __restrict__ h1T)
{
    constexpr int RPB = 32, LDT = Dc + 8;          // 776
    __shared__ unsigned short T[RPB * LDT];        // 48.5 KB
    const int b   = blockIdx.y;
    const int t   = tasks[b];
    const int s0  = blockIdx.x * RPB;
    const int tid = threadIdx.x;
    const int r   = tid >> 3;                      // 0..31
    const int d0  = (tid & 7) * 96;                // 0..672

    const float* xr = x + ((long)b * Sc + s0 + r) * Dc + d0;
    float4 v[24];
    float s = 0.f, q = 0.f;
    #pragma unroll
    for (int i = 0; i < 24; i++) {
        v[i] = reinterpret_cast<const float4*>(xr)[i];
        s += v[i].x + v[i].y + v[i].z + v[i].w;
        q += v[i].x * v[i].x + v[i].y * v[i].y + v[i].z * v[i].z + v[i].w * v[i].w;
    }
    #pragma unroll
    for (int o = 1; o < 8; o <<= 1) { s += __shfl_xor(s, o); q += __shfl_xor(q, o); }
    const float mu   = s * (1.0f / Dc);
    const float var  = fmaxf(q * (1.0f / Dc) - mu * mu, 0.0f);
    const float rstd = 1.0f / sqrtf(var + 1e-5f);
    const float* ga = cln + (long)t * 2 * Dc + d0;
    const float* be = ga + Dc;
    #pragma unroll
    for (int i = 0; i < 24; i++) {
        const float4 g4 = reinterpret_cast<const float4*>(ga)[i];
        const float4 b4 = reinterpret_cast<const float4*>(be)[i];
        unsigned short* dst = &T[r * LDT + d0 + i * 4];
        dst[0] = (unsigned short)(__builtin_bit_cast(unsigned, (float)((__bf16)(g4.x * ((v[i].x - mu) * rstd) + b4.x))) >> 16);
        // simpler: compute bf16 then bitcast
        __bf16 o0 = (__bf16)(g4.x * ((v[i].x - mu) * rstd) + b4.x);
        __bf16 o1 = (__bf16)(g4.y * ((v[i].y - mu) * rstd) + b4.y);
        __bf16 o2 = (__bf16)(g4.z * ((v[i].z - mu) * rstd) + b4.z);
        __bf16 o3 = (__bf16)(g4.w * ((v[i].w - mu) * rstd) + b4.w);
        dst[0] = __builtin_bit_cast(unsigned short, o0);
        dst[1] = __builtin_bit_cast(unsigned short, o1);
        dst[2] = __builtin_bit_cast(unsigned short, o2);
        dst[3] = __builtin_bit_cast(unsigned short, o3);
    }
    __syncthreads();
    // phase 2: each thread writes 3 columns d (64B contiguous in s)
    #pragma unroll
    for (int c = 0; c < 3; c++) {
        const int d = tid + c * 256;
        unsigned short tmp[32];
        #pragma unroll
        for (int e = 0; e < 32; e++) tmp[e] = T[e * LDT + d];
        __bf16* dst = h1T + ((long)b * Dc + d) * Sc + s0;
        #pragma unroll
        for (int u = 0; u < 4; u++)
            reinterpret_cast<uint4*>(dst)[u] = reinterpret_cast<const uint4*>(tmp)[u];
    }
}

// ---------------- conditional LayerNorm, bf16 input -> bf16 ----------------
__global__ __launch_bounds__(192) void cond_ln_b(
    const __bf16* __restrict__ x, const int* __restrict__ tasks,
    const float* __restrict__ cln, __bf16* __restrict__ out)
{
    const int row = blockIdx.x;
    const int b   = row >> 10;
    const int t   = tasks[b];
    const int tid = threadIdx.x;
    const ushort4 u = reinterpret_cast<const ushort4*>(x + (long)row * Dc)[tid];
    const float v0 = bf2f(u.x), v1 = bf2f(u.y), v2 = bf2f(u.z), v3 = bf2f(u.w);
    float s = v0 + v1 + v2 + v3;
    float q = v0 * v0 + v1 * v1 + v2 * v2 + v3 * v3;
    #pragma unroll
    for (int o = 1; o < 64; o <<= 1) { s += __shfl_xor(s, o); q += __shfl_xor(q, o); }
    __shared__ float ss[3], qs[3];
    const int w = tid >> 6;
    if ((tid & 63) == 0) { ss[w] = s; qs[w] = q; }
    __syncthreads();
    s = ss[0] + ss[1] + ss[2];
    q = qs[0] + qs[1] + qs[2];
    const float mu   = s * (1.0f / Dc);
    const float var  = fmaxf(q * (1.0f / Dc) - mu * mu, 0.0f);
    const float rstd = 1.0f / sqrtf(var + 1e-5f);
    const float4 g  = reinterpret_cast<const float4*>(cln + (long)t * 2 * Dc)[tid];
    const float4 be = reinterpret_cast<const float4*>(cln + (long)t * 2 * Dc + Dc)[tid];
    bf16x4 o;
    o[0] = (__bf16)(g.x * ((v0 - mu) * rstd) + be.x);
    o[1] = (__bf16)(g.y * ((v1 - mu) * rstd) + be.y);
    o[2] = (__bf16)(g.z * ((v2 - mu) * rstd) + be.z);
    o[3] = (__bf16)(g.w * ((v3 - mu) * rstd) + be.w);
    *reinterpret_cast<bf16x4*>(out + (long)row * Dc + tid * 4) = o;
}

// ---------------- bf16 TN MFMA GEMM (proven round-2 inner loop) ------------
// C[sel_b](MxN) = A[selA](MxK, k-contig, lda) * B[selB](NxK, k-contig, ldb)^T
// ATASK=1: A task-indexed, B batch-indexed; else A batch, B task.
// RESM: 0 none, 1 fp32 residual, 2 bf16 residual. OUTF32: fp32 vs bf16 out.
// Requires K % 8 == 0 (zero-padded), M % 128 == 0.
template<int DOGELU, int RESM, int OUTF32, int ATASK>
__global__ __launch_bounds__(256, 4) void gemm_tn(
    const __bf16* __restrict__ A, long sA, int lda,
    const __bf16* __restrict__ B, long sB, int ldb,
    const void* __restrict__ R, long sR,
    void* __restrict__ C, long sC, int ldc,
    const int* __restrict__ tasks, int M, int N, int K)
{
    constexpr int BM = 128, BN = 128, BK = 64, LDP = 72;
    __shared__ unsigned short As[BM][LDP];
    __shared__ unsigned short Bs[BN][LDP];

    const int b = blockIdx.z;
    const int t = tasks[b];
    const __bf16* Ab = A + (ATASK ? (long)t : (long)b) * sA;
    const __bf16* Bb = B + (ATASK ? (long)b : (long)t) * sB;
    const int m0 = blockIdx.y * BM, n0 = blockIdx.x * BN;
    const int tid = threadIdx.x, lane = tid & 63, wid = tid >> 6;
    const int wm = (wid >> 1) * 64, wn = (wid & 1) * 64;
    const int l15 = lane & 15, l4 = lane >> 4;

    f32x4 acc[4][4];
    #pragma unroll
    for (int i = 0; i < 4; i++)
        #pragma unroll
        for (int j = 0; j < 4; j++)
            acc[i][j] = (f32x4){0.f, 0.f, 0.f, 0.f};

    for (int k0 = 0; k0 < K; k0 += BK) {
        #pragma unroll
        for (int rep = 0; rep < 4; rep++) {
            const int c = rep * 256 + tid;
            const int m = c >> 3, kc = (c & 7) * 8;
            const int gm = m0 + m, gk = k0 + kc;
            uint4 v = {0u, 0u, 0u, 0u};
            if (gm < M && gk < K)
                v = *reinterpret_cast<const uint4*>(Ab + (long)gm * lda + gk);
            *reinterpret_cast<uint4*>(&As[m][kc]) = v;
        }
        #pragma unroll
        for (int rep = 0; rep < 4; rep++) {
            const int c = rep * 256 + tid;
            const int n = c >> 3, kc = (c & 7) * 8;
            const int gk = k0 + kc, gn = n0 + n;
            uint4 v = {0u, 0u, 0u, 0u};
            if (gn < N && gk < K)
                v = *reinterpret_cast<const uint4*>(Bb + (long)gn * ldb + gk);
            *reinterpret_cast<uint4*>(&Bs[n][kc]) = v;
        }
        __syncthreads();
        #pragma unroll
        for (int h = 0; h < 2; h++) {
            bf16x8 af[4], bfr[4];
            #pragma unroll
            for (int i = 0; i < 4; i++)
                af[i] = *reinterpret_cast<const bf16x8*>(&As[wm + i * 16 + l15][h * 32 + l4 * 8]);
            #pragma unroll
            for (int j = 0; j < 4; j++)
                bfr[j] = *reinterpret_cast<const bf16x8*>(&Bs[wn + j * 16 + l15][h * 32 + l4 * 8]);
            #pragma unroll
            for (int i = 0; i < 4; i++)
                #pragma unroll
                for (int j = 0; j < 4; j++)
                    acc[i][j] = __builtin_amdgcn_mfma_f32_16x16x32_bf16(af[i], bfr[j], acc[i][j], 0, 0, 0);
        }
        __syncthreads();
    }

    float*  Cf = (float*)C  + (long)b * sC;
    __bf16* Ch = (__bf16*)C + (long)b * sC;
    const float*  Rf = (RESM == 1) ? ((const float*)R  + (long)b * sR) : nullptr;
    const __bf16* Rh = (RESM == 2) ? ((const __bf16*)R + (long)b * sR) : nullptr;

    #pragma unroll
    for (int i = 0; i < 4; i++) {
        #pragma unroll
        for (int j = 0; j < 4; j++) {
            const int gn = n0 + wn + j * 16 + l15;
            if (gn >= N) continue;
            #pragma unroll
            for (int r = 0; r < 4; r++) {
                const int gm = m0 + wm + i * 16 + l4 * 4 + r;
                if (gm >= M) continue;
                float v = acc[i][j][r];
                if (DOGELU) v = 0.5f * v * (1.0f + erff(v * 0.70710678118654752f));
                if (RESM == 1) v += Rf[(long)gm * ldc + gn];
                if (RESM == 2) v += (float)Rh[(long)gm * ldc + gn];
                if (OUTF32) Cf[(long)gm * ldc + gn] = v;
                else        Ch[(long)gm * ldc + gn] = (__bf16)v;
            }
        }
    }
}

extern "C" void kernel_launch(void* const* d_in, const int* in_sizes, int n_in,
                              void* d_out, int out_size, void* d_ws, size_t ws_size,
                              hipStream_t stream) {
    const float* x      = (const float*)d_in[0];
    const int*   tasks  = (const int*)  d_in[1];
    const float* cln1   = (const float*)d_in[2];
    const float* cln2   = (const float*)d_in[3];
    const float* w1_tok = (const float*)d_in[4];
    const float* w2_tok = (const float*)d_in[5];
    const float* w1_ch  = (const float*)d_in[6];
    const float* w2_ch  = (const float*)d_in[7];
    float* out = (float*)d_out;

    // ---- workspace layout (bytes), ~151 MB total ----
    char* ws = (char*)d_ws;
    const long oT1 = 0;                               // wT1: 10 x ISp x Sc
    const long oT2 = oT1 + (long)10 * ISp * Sc * 2;   // wT2: 10 x Sc x ISp
    const long oC1 = oT2 + (long)10 * Sc * ISp * 2;   // wC1: 10 x IDp x Dc
    const long oC2 = oC1 + (long)10 * IDp * Dc * 2;   // wC2: 10 x Dc x IDp
    const long oA  = oC2 + (long)10 * Dc * IDp * 2;   // slabA: h1T then x1 (B*D*S bf16)
    const long oG  = oA  + (long)Bc * Dc * Sc * 2;    // gbf: GT / G2
    __bf16* wT1  = (__bf16*)(ws + oT1);
    __bf16* wT2  = (__bf16*)(ws + oT2);
    __bf16* wC1  = (__bf16*)(ws + oC1);
    __bf16* wC2  = (__bf16*)(ws + oC2);
    __bf16* h1T  = (__bf16*)(ws + oA);
    __bf16* x1   = (__bf16*)(ws + oA);                // reuses h1T (dead after GEMM3)
    __bf16* gbf  = (__bf16*)(ws + oG);
    __bf16* h2   = (__bf16*)d_out;                    // bf16 scratch inside d_out

    const dim3 blk(256);
    auto cdiv = [](long a, long b) { return (int)((a + b - 1) / b); };

    // weight conversions (task-major, zero-padded)
    cvt_pad<<<cdiv((long)10 * ISp * (Sc / 8), 256), blk, 0, stream>>>(w1_tok, wT1, ISc, ISp, Sc, Sc);
    cvt_pad<<<cdiv((long)10 * Sc * (ISp / 8), 256), blk, 0, stream>>>(w2_tok, wT2, Sc, Sc, ISc, ISp);
    cvt_pad<<<cdiv((long)10 * IDp * (Dc / 8), 256), blk, 0, stream>>>(w1_ch, wC1, IDc, IDp, Dc, Dc);
    cvt_pad<<<cdiv((long)10 * Dc * (IDp / 8), 256), blk, 0, stream>>>(w2_ch, wC2, Dc, Dc, IDc, IDp);

    // 1) h1T = condLN(x, cln1)^T   (B, D, S) bf16
    ln1_t<<<dim3(Sc / 32, Bc), blk, 0, stream>>>(x, tasks, cln1, h1T);

    // 2) GT = gelu(h1T @ W1tok[t]^T)   M=D, N=ISp, K=S
    gemm_tn<1, 0, 0, 0><<<dim3(cdiv(ISp, 128), Dc / 128, Bc), blk, 0, stream>>>(
        h1T, (long)Dc * Sc, Sc,
        wT1, (long)ISp * Sc, Sc,
        nullptr, 0,
        gbf, (long)Dc * ISp, ISp,
        tasks, Dc, ISp, Sc);

    // 3) x1 = x + W2tok[t] @ GT^T   M=S, N=D, K=ISp ; fp32 res; bf16 out
    gemm_tn<0, 1, 0, 1><<<dim3(Dc / 128, Sc / 128, Bc), blk, 0, stream>>>(
        wT2, (long)Sc * ISp, ISp,
        gbf, (long)Dc * ISp, ISp,
        x, (long)Sc * Dc,
        x1, (long)Sc * Dc, Dc,
        tasks, Sc, Dc, ISp);

    // 4) h2 = condLN(x1, cln2)  (bf16, in d_out scratch)
    cond_ln_b<<<Bc * Sc, 192, 0, stream>>>(x1, tasks, cln2, h2);

    // 5) G2 = gelu(h2 @ W1ch[t]^T)   M=S, N=IDp, K=D
    gemm_tn<1, 0, 0, 0><<<dim3(cdiv(IDp, 128), Sc / 128, Bc), blk, 0, stream>>>(
        h2, (long)Sc * Dc, Dc,
        wC1, (long)IDp * Dc, Dc,
        nullptr, 0,
        gbf, (long)Sc * IDp, IDp,
        tasks, Sc, IDp, Dc);

    // 6) out = x1 + G2 @ W2ch[t]^T   M=S, N=D, K=IDp ; bf16 res; fp32 out
    gemm_tn<0, 2, 1, 0><<<dim3(Dc / 128, Sc / 128, Bc), blk, 0, stream>>>(
        gbf, (long)Sc * IDp, IDp,
        wC2, (long)Dc * IDp, IDp,
        x1, (long)Sc * Dc,
        out, (long)Sc * Dc, Dc,
        tasks, Sc, Dc, IDp);
}